// Round 9
// baseline (600.654 us; speedup 1.0000x reference)
//
#include <hip/hip_runtime.h>

typedef unsigned short u16;
typedef unsigned int   u32;
typedef __attribute__((ext_vector_type(8))) __bf16 bf16x8;
typedef __attribute__((ext_vector_type(4))) float  f32x4;
typedef __attribute__((ext_vector_type(4))) u32    u32x4;

#define AS1 __attribute__((address_space(1)))
#define AS3 __attribute__((address_space(3)))

// B=4096, K=64, D=128, H=2048, V=10000, IN=8640
// Permuted inp layout per row: [0,128) u | [128,8320) v | [8320,8576) extras | [8576,8640) pop

__device__ __forceinline__ u16 f2bf(float f) {
  u32 u = __builtin_bit_cast(u32, f);
  u += 0x7fffu + ((u >> 16) & 1u);   // RNE
  return (u16)(u >> 16);
}

__device__ __forceinline__ float wred(float v) {
#pragma unroll
  for (int off = 32; off > 0; off >>= 1) v += __shfl_xor(v, off, 64);
  return v;
}

__device__ __forceinline__ void stage16(const u16* g, u16* l) {
  __builtin_amdgcn_global_load_lds((const AS1 void*)g, (AS3 void*)l, 16, 0, 0);
}

// ---------------- feature kernel v2 (R8) ----------------
__global__ __launch_bounds__(256) void feature_kernel(
    const float* __restrict__ te, const int* __restrict__ nidx,
    const float* __restrict__ freq, const float* __restrict__ lut,
    u16* __restrict__ inp)
{
  const int b = blockIdx.x;
  const int t = threadIdx.x;
  const int l = t & 63, w = t >> 6;
  __shared__ float u_sh[128];
  __shared__ float squ_sh;

  if (t < 128) u_sh[t] = te[(size_t)b * 128 + t];
  __syncthreads();
  if (w == 0) {
    float p = u_sh[l] * u_sh[l] + u_sh[l + 64] * u_sh[l + 64];
    p = wred(p);
    if (l == 0) squ_sh = p;
  }
  const size_t rb = (size_t)b * 8640;
  if (t < 64) {
    float2 u2 = *(const float2*)&u_sh[t * 2];
    u32 pk = (u32)f2bf(u2.x) | ((u32)f2bf(u2.y) << 16);
    *(u32*)&inp[rb + t * 2] = pk;
  }
  __syncthreads();

  const float squ = squ_sh;
  const float rsq = 1.0f - squ;
  const float2 u2 = *(const float2*)&u_sh[l * 2];

#pragma unroll
  for (int mk = 0; mk < 4; ++mk) {
    const int kbase = w * 16 + mk * 4;
    int idx[4]; float2 v2[4]; float sqv[4], dot[4];
#pragma unroll
    for (int j = 0; j < 4; j++) {
      idx[j] = nidx[b * 64 + kbase + j];
      v2[j] = *(const float2*)&lut[(size_t)idx[j] * 128 + l * 2];
    }
#pragma unroll
    for (int j = 0; j < 4; j++) {
      sqv[j] = v2[j].x * v2[j].x + v2[j].y * v2[j].y;
      dot[j] = u2.x * v2[j].x + u2.y * v2[j].y;
    }
#pragma unroll
    for (int off = 32; off > 0; off >>= 1) {
#pragma unroll
      for (int j = 0; j < 4; j++) {
        sqv[j] += __shfl_xor(sqv[j], off, 64);
        dot[j] += __shfl_xor(dot[j], off, 64);
      }
    }
#pragma unroll
    for (int j = 0; j < 4; j++) {
      u32 pk = (u32)f2bf(v2[j].x) | ((u32)f2bf(v2[j].y) << 16);
      *(u32*)&inp[rb + 128 + (size_t)(kbase + j) * 128 + l * 2] = pk;
    }
    float poin[4], cosv[4];
#pragma unroll
    for (int j = 0; j < 4; j++) {
      const float sqd = squ + sqv[j] - 2.0f * dot[j];
      float x = 1.0f + 2.0f * sqd / (rsq * (1.0f - sqv[j]));
      x = fmaxf(x, 1.0f + 1e-5f);
      poin[j] = logf(x + sqrtf(x * x - 1.0f));
      cosv[j] = dot[j] / fmaxf(sqrtf(squ * sqv[j]), 1e-8f);
    }
    if (l == 0) {
      u32x4 e0, e1;
#pragma unroll
      for (int j = 0; j < 2; j++) {
        e0[2 * j]     = (u32)f2bf(poin[j]) | ((u32)f2bf(cosv[j]) << 16);
        e0[2 * j + 1] = (u32)f2bf(dot[j])  | ((u32)f2bf(dot[j])  << 16);
        e1[2 * j]     = (u32)f2bf(poin[2 + j]) | ((u32)f2bf(cosv[2 + j]) << 16);
        e1[2 * j + 1] = (u32)f2bf(dot[2 + j])  | ((u32)f2bf(dot[2 + j])  << 16);
      }
      *(u32x4*)&inp[rb + 8320 + kbase * 4]     = e0;
      *(u32x4*)&inp[rb + 8320 + kbase * 4 + 8] = e1;
      u16 pp[4];
#pragma unroll
      for (int j = 0; j < 4; j++) pp[j] = f2bf(log1pf(freq[idx[j]]));
      *(u32*)&inp[rb + 8576 + kbase]     = (u32)pp[0] | ((u32)pp[1] << 16);
      *(u32*)&inp[rb + 8576 + kbase + 2] = (u32)pp[2] | ((u32)pp[3] << 16);
    }
  }
}

// -------- W1 transpose with feature permutation (R8) --------
__device__ __forceinline__ int w1_orig_row(int p) {
  if (p < 128) return p;
  if (p < 8320) { int q = p - 128;  return 128 + (q >> 7) * 133 + (q & 127); }
  if (p < 8576) { int q = p - 8320; return 128 + (q >> 2) * 133 + 128 + (q & 3); }
  return 128 + (p - 8576) * 133 + 132;
}

__global__ __launch_bounds__(256) void transpose_w1(
    const float* __restrict__ in, u16* __restrict__ out)
{
  __shared__ u16 ls[64][68];
  const int p0 = (blockIdx.x >> 5) << 6;
  const int h0 = (blockIdx.x & 31) << 6;
  const int t = threadIdx.x;
  const int hl = t & 63, q = t >> 6;
#pragma unroll
  for (int i = 0; i < 16; i++) {
    int pl = i * 4 + q;
    int orig = w1_orig_row(p0 + pl);
    ls[hl][pl] = f2bf(in[(size_t)orig * 2048 + h0 + hl]);
  }
  __syncthreads();
  const int pp = t & 15, hq = t >> 4;
#pragma unroll
  for (int i = 0; i < 4; i++) {
    int hc = i * 16 + hq;
    uint2 vv = *(const uint2*)&ls[hc][pp * 4];
    *(uint2*)&out[(size_t)(h0 + hc) * 8640 + p0 + pp * 4] = vv;
  }
}

// -------- generic transpose+convert (R8) --------
__global__ __launch_bounds__(256) void transpose_conv(
    const float* __restrict__ in, u16* __restrict__ out, int R, int C)
{
  __shared__ u16 ls[64][68];
  const int tiles_c = C >> 6;
  const int r0 = (blockIdx.x / tiles_c) << 6;
  const int c0 = (blockIdx.x % tiles_c) << 6;
  const int t = threadIdx.x;
  const int cl = t & 63, q = t >> 6;
#pragma unroll
  for (int i = 0; i < 16; i++) {
    int rl = i * 4 + q;
    ls[cl][rl] = f2bf(in[(size_t)(r0 + rl) * C + c0 + cl]);
  }
  __syncthreads();
  const int pp = t & 15, cq = t >> 4;
#pragma unroll
  for (int i = 0; i < 4; i++) {
    int cc = i * 16 + cq;
    uint2 vv = *(const uint2*)&ls[cc][pp * 4];
    *(uint2*)&out[(size_t)(c0 + cc) * R + r0 + pp * 4] = vv;
  }
}

// ======== gemm9: C = relu(A(M,Kd)*BT(N,Kd)^T + bias), out bf16 ========
// BM=256 BN=128 BK=64. 8 waves = 2 kg x (2Mx2N), wave tile 128x64 (kg K32
// halves). A-operand: GLOBAL->REG double-buffer (named aR/aS, 2-unrolled —
// rule #20), depth-1 pipeline. B: gload_lds ring-3 x 16KB (T2 pre-swizzled
// source + swizzled ds_read, R6-verified). Counted-vmcnt ledger (steady
// queue = [A(ti)8, B(ti+1)2, A(ti+1)8, B(ti+2)2]): vmcnt(12) retires A(ti)
// before MFMA, vmcnt(10) retires B(ti+1) before the one barrier/interval;
// tail (last 2 intervals) drains vmcnt(0). LDS/interval: 32KB rd + 16KB wr
// (~420cyc) vs R6's 144KB (~1258cyc); A rides VMEM/L2 port (~970cyc) which
// overlaps MFMA (1242cyc) -> target interval ~1500cyc (was 2500).
__global__ __launch_bounds__(512, 2) void gemm9(
    const u16* __restrict__ A, const u16* __restrict__ BT,
    const float* __restrict__ bias, u16* __restrict__ out,
    int N, int Kd)
{
  extern __shared__ u16 lds[];   // 3 * 8192 u16 = 48KB (B ring)
  const int t = threadIdx.x, l = t & 63, w = t >> 6;
  const int nb = N >> 7;
  const int cpx = gridDim.x >> 3;
  const int bid = (blockIdx.x & 7) * cpx + (blockIdx.x >> 3);
  const int bm = bid / nb, bn = bid % nb;
  const int m0 = bm << 8, n0 = bn << 7;

  const int kg = w >> 2;
  const int p  = w & 3;
  const int vm = p >> 1, vn = p & 1;

  const size_t lda = (size_t)Kd;
  const int NT = Kd >> 6;

  // B staging consts (pre-swizzled global source), 2 gload_lds per wave
  const int sr = l >> 3;
  const int q  = (l & 7) ^ (sr & 7);
  const u16* sB = BT + (size_t)(n0 + w * 8 + sr) * lda + q * 8;
  const int dL = w * 512 + l * 8;

  // B reader consts (swizzled ds_read)
  const int rl  = l & 15;
  const int swz = ((kg * 4 + (l >> 4)) ^ (l & 7)) * 8;
  const int bOff = (vn * 64 + rl) * 64 + swz;

  // A direct-load consts: lane l -> row m0+vm*128+rl (+mi*16), k = kg*32+(l>>4)*8
  const u16* pA = A + (size_t)(m0 + vm * 128 + rl) * lda + kg * 32 + (l >> 4) * 8;

  f32x4 acc[8][4] = {};
  bf16x8 aR[8], aS[8], bfr[4];

  auto stageB = [&](int o, int tt) {
    const size_t kt = (size_t)tt * 64;
    stage16(sB + kt,            lds + o + dL);
    stage16(sB + 64 * lda + kt, lds + o + 4096 + dL);
  };
  auto loadA = [&](bf16x8* d, int tt) {
    const size_t kt = (size_t)tt * 64;
#pragma unroll
    for (int mi = 0; mi < 8; mi++)
      d[mi] = *(const bf16x8*)(pA + (size_t)mi * 16 * lda + kt);
  };
  auto rdB = [&](int o) {
#pragma unroll
    for (int ni = 0; ni < 4; ni++)
      bfr[ni] = *(const bf16x8*)&lds[o + bOff + ni * 1024];
  };
  auto mmq = [&](const bf16x8* a) {
    __builtin_amdgcn_s_setprio(1);
#pragma unroll
    for (int mi = 0; mi < 8; mi++)
#pragma unroll
      for (int ni = 0; ni < 4; ni++)
        acc[mi][ni] = __builtin_amdgcn_mfma_f32_16x16x32_bf16(a[mi], bfr[ni], acc[mi][ni], 0, 0, 0);
    __builtin_amdgcn_s_setprio(0);
  };

  int o0 = 0, o1 = 8192, o2 = 16384;
  // prologue: queue = [B(0)2, A(0)8, B(1)2] = 12; vmcnt(10) retires B(0)
  stageB(o0, 0);
  loadA(aR, 0);
  stageB(o1, 1);
  asm volatile("s_waitcnt vmcnt(10)" ::: "memory");
  __builtin_amdgcn_s_barrier();

  for (int ti = 0; ti < NT; ti += 2) {
    {   // sub A: j=ti, compute aR, load aS=A(ti+1)
      const int j = ti;
      const bool steady = (j + 2 < NT);
      if (j + 1 < NT) loadA(aS, j + 1);
      if (steady) stageB(o2, j + 2);
      rdB(o0);
      if (steady) asm volatile("s_waitcnt vmcnt(12)" ::: "memory");
      else        asm volatile("s_waitcnt vmcnt(0)"  ::: "memory");
      asm volatile("s_waitcnt lgkmcnt(0)" ::: "memory");
      __builtin_amdgcn_sched_barrier(0);
      mmq(aR);
      if (steady) asm volatile("s_waitcnt vmcnt(10)" ::: "memory");
      else        asm volatile("s_waitcnt vmcnt(0)"  ::: "memory");
      __builtin_amdgcn_s_barrier();
      const int tmp = o0; o0 = o1; o1 = o2; o2 = tmp;
    }
    if (ti + 1 < NT) {   // sub B: j=ti+1, compute aS, load aR=A(ti+2)
      const int j = ti + 1;
      const bool steady = (j + 2 < NT);
      if (j + 1 < NT) loadA(aR, j + 1);
      if (steady) stageB(o2, j + 2);
      rdB(o0);
      if (steady) asm volatile("s_waitcnt vmcnt(12)" ::: "memory");
      else        asm volatile("s_waitcnt vmcnt(0)"  ::: "memory");
      asm volatile("s_waitcnt lgkmcnt(0)" ::: "memory");
      __builtin_amdgcn_sched_barrier(0);
      mmq(aS);
      if (steady) asm volatile("s_waitcnt vmcnt(10)" ::: "memory");
      else        asm volatile("s_waitcnt vmcnt(0)"  ::: "memory");
      __builtin_amdgcn_s_barrier();
      const int tmp = o0; o0 = o1; o1 = o2; o2 = tmp;
    }
  }

  // ---- kg-combine via LDS (chunked to fit 48KB), then epilogue ----
  __syncthreads();
  float* pl = (float*)lds;
  const int rq = l >> 4, rl2 = l & 15;
#pragma unroll
  for (int h = 0; h < 4; h++) {
    if (kg == 1) {
#pragma unroll
      for (int mi2 = 0; mi2 < 2; mi2++)
#pragma unroll
        for (int ni = 0; ni < 4; ni++)
          *(f32x4*)&pl[p * 2048 + (mi2 * 4 + ni) * 256 + l * 4] = acc[h * 2 + mi2][ni];
    }
    __syncthreads();
    if (kg == 0) {
#pragma unroll
      for (int mi2 = 0; mi2 < 2; mi2++) {
#pragma unroll
        for (int ni = 0; ni < 4; ni++) {
          f32x4 p2 = *(const f32x4*)&pl[p * 2048 + (mi2 * 4 + ni) * 256 + l * 4];
          const int mi = h * 2 + mi2;
          const int col = n0 + vn * 64 + ni * 16 + rl2;
          const float bv = bias[col];
#pragma unroll
          for (int j = 0; j < 4; j++) {
            const int row = m0 + vm * 128 + mi * 16 + rq * 4 + j;
            float vv = acc[mi][ni][j] + p2[j] + bv;
            out[(size_t)row * N + col] = f2bf(fmaxf(vv, 0.0f));
          }
        }
      }
    }
    __syncthreads();
  }
}

// -------- gemm4 split-K partial (R8) --------
__global__ __launch_bounds__(256, 2) void gemm4_part(
    const u16* __restrict__ A, const u16* __restrict__ BT,
    float* __restrict__ pbuf)
{
  __shared__ u16 lsA[2 * 128 * 32];
  __shared__ u16 lsB[2 * 64 * 32];
  const int t = threadIdx.x, l = t & 63, w = t >> 6;
  const int bmx = blockIdx.x & 31, sk = blockIdx.x >> 5;
  const int m0 = bmx << 7, k0 = sk << 9;
  float* pout = pbuf + (size_t)sk * 262144;
  const int wm = w >> 1, wn = w & 1;

  f32x4 acc[4][2] = {};
  const int srow = l >> 2, scol = (l & 3) * 8;

  const u16* pA0 = A  + (size_t)(m0 + w * 16 + srow)      * 2048 + scol + k0;
  const u16* pA1 = A  + (size_t)(m0 + 64 + w * 16 + srow) * 2048 + scol + k0;
  const u16* pB0 = BT + (size_t)(w * 16 + srow)           * 2048 + scol + k0;

  auto stage = [&](int buf, int kt) {
    u16* dA = lsA + buf * 4096;
    u16* dB = lsB + buf * 2048;
    stage16(pA0 + kt, dA + w * 512);
    stage16(pA1 + kt, dA + 2048 + w * 512);
    stage16(pB0 + kt, dB + w * 512);
  };

  stage(0, 0);
  __syncthreads();

  const int kk = (l >> 4) * 8;
  const int rl = l & 15;
  int cur = 0;
  for (int kt = 0; kt < 512; kt += 32) {
    if (kt + 32 < 512) stage(cur ^ 1, kt + 32);
    const u16* sA = lsA + cur * 4096;
    const u16* sB = lsB + cur * 2048;
    bf16x8 a[4], bb[2];
#pragma unroll
    for (int mi = 0; mi < 4; mi++)
      a[mi] = *(const bf16x8*)&sA[(wm * 64 + mi * 16 + rl) * 32 + kk];
#pragma unroll
    for (int ni = 0; ni < 2; ni++)
      bb[ni] = *(const bf16x8*)&sB[(wn * 32 + ni * 16 + rl) * 32 + kk];
#pragma unroll
    for (int mi = 0; mi < 4; mi++)
#pragma unroll
      for (int ni = 0; ni < 2; ni++)
        acc[mi][ni] = __builtin_amdgcn_mfma_f32_16x16x32_bf16(a[mi], bb[ni], acc[mi][ni], 0, 0, 0);
    __syncthreads();
    cur ^= 1;
  }

  const int rq = l >> 4, rl2 = l & 15;
#pragma unroll
  for (int mi = 0; mi < 4; mi++)
#pragma unroll
    for (int ni = 0; ni < 2; ni++) {
      const int col = wn * 32 + ni * 16 + rl2;
#pragma unroll
      for (int j = 0; j < 4; j++) {
        const int row = m0 + wm * 64 + mi * 16 + rq * 4 + j;
        pout[(size_t)row * 64 + col] = acc[mi][ni][j];
      }
    }
}

// -------- combine: sum 4 partials + bias -> sigmoid + BCE partials --------
__global__ __launch_bounds__(256) void gemm4_combine(
    const float* __restrict__ pbuf, const float* __restrict__ bias,
    const float* __restrict__ oneh, float* __restrict__ dist,
    float* __restrict__ part2)
{
  __shared__ float red[256];
  const int t = threadIdx.x;
  const size_t base = (size_t)blockIdx.x * 1024 + t * 4;
  f32x4 s = *(const f32x4*)&pbuf[base];
  s += *(const f32x4*)&pbuf[base + 262144];
  s += *(const f32x4*)&pbuf[base + 524288];
  s += *(const f32x4*)&pbuf[base + 786432];
  const int col0 = (int)(base & 63);
  f32x4 th = *(const f32x4*)&oneh[base];
  float lsum = 0.0f;
  f32x4 dv;
#pragma unroll
  for (int j = 0; j < 4; j++) {
    const float x = s[j] + bias[col0 + j];
    dv[j] = 1.0f / (1.0f + expf(-x));
    lsum += fmaxf(x, 0.0f) - x * th[j] + log1pf(expf(-fabsf(x)));
  }
  *(f32x4*)&dist[base] = dv;
  red[t] = lsum;
  __syncthreads();
  for (int s2 = 128; s2 > 0; s2 >>= 1) {
    if (t < s2) red[t] += red[t + s2];
    __syncthreads();
  }
  if (t == 0) part2[blockIdx.x] = red[0];
}

__global__ void loss_final(const float* __restrict__ part2, float* __restrict__ outloss) {
  const int l = threadIdx.x;
  float v = 0.0f;
#pragma unroll
  for (int i = 0; i < 4; i++) v += part2[l + i * 64];
  v = wred(v);
  if (l == 0) outloss[0] = v * (1.0f / 262144.0f);
}

// ---------------- launch ----------------
extern "C" void kernel_launch(void* const* d_in, const int* in_sizes, int n_in,
                              void* d_out, int out_size, void* d_ws, size_t ws_size,
                              hipStream_t stream)
{
  const float* te   = (const float*)d_in[0];
  const int*   nidx = (const int*)  d_in[1];
  const float* oneh = (const float*)d_in[2];
  const float* freq = (const float*)d_in[3];
  const float* lut  = (const float*)d_in[4];
  const float* W1   = (const float*)d_in[5];
  const float* b1   = (const float*)d_in[6];
  const float* Wh1  = (const float*)d_in[7];
  const float* bh1  = (const float*)d_in[8];
  const float* Wh2  = (const float*)d_in[9];
  const float* bh2  = (const float*)d_in[10];
  const float* W2   = (const float*)d_in[11];
  const float* b2   = (const float*)d_in[12];

  float* dist  = (float*)d_out;          // 4096*64
  float* lossp = dist + 262144;          // +1

  size_t off = 0;
  char* base = (char*)d_ws;
  auto alloc = [&](size_t bytes) { char* p = base + off; off += (bytes + 255) & ~(size_t)255; return p; };
  u16* inp   = (u16*)alloc((size_t)4096 * 8640 * 2);
  u16* w1t   = (u16*)alloc((size_t)2048 * 8640 * 2);
  u16* wh1t  = (u16*)alloc((size_t)2048 * 2048 * 2);
  u16* wh2t  = (u16*)alloc((size_t)2048 * 2048 * 2);
  u16* w2t   = (u16*)alloc((size_t)64 * 2048 * 2);
  u16* h1    = (u16*)alloc((size_t)4096 * 2048 * 2);
  float* part2 = (float*)alloc(1024);
  u16* h2 = inp;                  // inp dead after GEMM1
  u16* h3 = w1t;                  // w1t dead after GEMM1
  float* pbuf = (float*)wh1t;     // wh1t dead after GEMM2; 4MB < 8.4MB
  if (off > ws_size) return;

  (void)hipFuncSetAttribute((const void*)gemm9,
                            hipFuncAttributeMaxDynamicSharedMemorySize, 49152);

  feature_kernel<<<4096, 256, 0, stream>>>(te, nidx, freq, lut, inp);
  transpose_w1 <<<135 * 32, 256, 0, stream>>>(W1, w1t);
  transpose_conv<<<32 * 32, 256, 0, stream>>>(Wh1, wh1t, 2048, 2048);
  transpose_conv<<<32 * 32, 256, 0, stream>>>(Wh2, wh2t, 2048, 2048);
  transpose_conv<<<32 * 1, 256, 0, stream>>>(W2, w2t, 2048, 64);

  gemm9<<<256, 512, 49152, stream>>>(inp, w1t, b1, h1, 2048, 8640);
  gemm9<<<256, 512, 49152, stream>>>(h1, wh1t, bh1, h2, 2048, 2048);
  gemm9<<<256, 512, 49152, stream>>>(h2, wh2t, bh2, h3, 2048, 2048);
  gemm4_part   <<<128, 256, 0, stream>>>(h3, w2t, pbuf);
  gemm4_combine<<<256, 256, 0, stream>>>(pbuf, b2, oneh, dist, part2);
  loss_final   <<<1, 64, 0, stream>>>(part2, lossp);
}

// Round 10
// 362.375 us; speedup vs baseline: 1.6575x; 1.6575x over previous
//
#include <hip/hip_runtime.h>

typedef unsigned short u16;
typedef unsigned int   u32;
typedef __attribute__((ext_vector_type(8)))  __bf16 bf16x8;
typedef __attribute__((ext_vector_type(4)))  float  f32x4;
typedef __attribute__((ext_vector_type(16))) float  f32x16;
typedef __attribute__((ext_vector_type(4)))  u32    u32x4;

#define AS1 __attribute__((address_space(1)))
#define AS3 __attribute__((address_space(3)))

// B=4096, K=64, D=128, H=2048, V=10000, IN=8640
// Permuted inp layout per row: [0,128) u | [128,8320) v | [8320,8576) extras | [8576,8640) pop

__device__ __forceinline__ u16 f2bf(float f) {
  u32 u = __builtin_bit_cast(u32, f);
  u += 0x7fffu + ((u >> 16) & 1u);   // RNE
  return (u16)(u >> 16);
}

__device__ __forceinline__ float wred(float v) {
#pragma unroll
  for (int off = 32; off > 0; off >>= 1) v += __shfl_xor(v, off, 64);
  return v;
}

__device__ __forceinline__ void stage16(const u16* g, u16* l) {
  __builtin_amdgcn_global_load_lds((const AS1 void*)g, (AS3 void*)l, 16, 0, 0);
}

// ---------------- feature kernel v2 (R8) ----------------
__global__ __launch_bounds__(256) void feature_kernel(
    const float* __restrict__ te, const int* __restrict__ nidx,
    const float* __restrict__ freq, const float* __restrict__ lut,
    u16* __restrict__ inp)
{
  const int b = blockIdx.x;
  const int t = threadIdx.x;
  const int l = t & 63, w = t >> 6;
  __shared__ float u_sh[128];
  __shared__ float squ_sh;

  if (t < 128) u_sh[t] = te[(size_t)b * 128 + t];
  __syncthreads();
  if (w == 0) {
    float p = u_sh[l] * u_sh[l] + u_sh[l + 64] * u_sh[l + 64];
    p = wred(p);
    if (l == 0) squ_sh = p;
  }
  const size_t rb = (size_t)b * 8640;
  if (t < 64) {
    float2 u2 = *(const float2*)&u_sh[t * 2];
    u32 pk = (u32)f2bf(u2.x) | ((u32)f2bf(u2.y) << 16);
    *(u32*)&inp[rb + t * 2] = pk;
  }
  __syncthreads();

  const float squ = squ_sh;
  const float rsq = 1.0f - squ;
  const float2 u2 = *(const float2*)&u_sh[l * 2];

#pragma unroll
  for (int mk = 0; mk < 4; ++mk) {
    const int kbase = w * 16 + mk * 4;
    int idx[4]; float2 v2[4]; float sqv[4], dot[4];
#pragma unroll
    for (int j = 0; j < 4; j++) {
      idx[j] = nidx[b * 64 + kbase + j];
      v2[j] = *(const float2*)&lut[(size_t)idx[j] * 128 + l * 2];
    }
#pragma unroll
    for (int j = 0; j < 4; j++) {
      sqv[j] = v2[j].x * v2[j].x + v2[j].y * v2[j].y;
      dot[j] = u2.x * v2[j].x + u2.y * v2[j].y;
    }
#pragma unroll
    for (int off = 32; off > 0; off >>= 1) {
#pragma unroll
      for (int j = 0; j < 4; j++) {
        sqv[j] += __shfl_xor(sqv[j], off, 64);
        dot[j] += __shfl_xor(dot[j], off, 64);
      }
    }
#pragma unroll
    for (int j = 0; j < 4; j++) {
      u32 pk = (u32)f2bf(v2[j].x) | ((u32)f2bf(v2[j].y) << 16);
      *(u32*)&inp[rb + 128 + (size_t)(kbase + j) * 128 + l * 2] = pk;
    }
    float poin[4], cosv[4];
#pragma unroll
    for (int j = 0; j < 4; j++) {
      const float sqd = squ + sqv[j] - 2.0f * dot[j];
      float x = 1.0f + 2.0f * sqd / (rsq * (1.0f - sqv[j]));
      x = fmaxf(x, 1.0f + 1e-5f);
      poin[j] = logf(x + sqrtf(x * x - 1.0f));
      cosv[j] = dot[j] / fmaxf(sqrtf(squ * sqv[j]), 1e-8f);
    }
    if (l == 0) {
      u32x4 e0, e1;
#pragma unroll
      for (int j = 0; j < 2; j++) {
        e0[2 * j]     = (u32)f2bf(poin[j]) | ((u32)f2bf(cosv[j]) << 16);
        e0[2 * j + 1] = (u32)f2bf(dot[j])  | ((u32)f2bf(dot[j])  << 16);
        e1[2 * j]     = (u32)f2bf(poin[2 + j]) | ((u32)f2bf(cosv[2 + j]) << 16);
        e1[2 * j + 1] = (u32)f2bf(dot[2 + j])  | ((u32)f2bf(dot[2 + j])  << 16);
      }
      *(u32x4*)&inp[rb + 8320 + kbase * 4]     = e0;
      *(u32x4*)&inp[rb + 8320 + kbase * 4 + 8] = e1;
      u16 pp[4];
#pragma unroll
      for (int j = 0; j < 4; j++) pp[j] = f2bf(log1pf(freq[idx[j]]));
      *(u32*)&inp[rb + 8576 + kbase]     = (u32)pp[0] | ((u32)pp[1] << 16);
      *(u32*)&inp[rb + 8576 + kbase + 2] = (u32)pp[2] | ((u32)pp[3] << 16);
    }
  }
}

// -------- fused transpose kernel: W1 (permuted) + Wh1 + Wh2 + W2 --------
__device__ __forceinline__ int w1_orig_row(int p) {
  if (p < 128) return p;
  if (p < 8320) { int q = p - 128;  return 128 + (q >> 7) * 133 + (q & 127); }
  if (p < 8576) { int q = p - 8320; return 128 + (q >> 2) * 133 + 128 + (q & 3); }
  return 128 + (p - 8576) * 133 + 132;
}

__device__ __forceinline__ void w1_tile(const float* __restrict__ in,
                                        u16* __restrict__ out, int tile,
                                        u16 (*ls)[68], int t)
{
  const int p0 = (tile >> 5) << 6;
  const int h0 = (tile & 31) << 6;
  const int hl = t & 63, q = t >> 6;
#pragma unroll
  for (int i = 0; i < 16; i++) {
    int pl = i * 4 + q;
    int orig = w1_orig_row(p0 + pl);
    ls[hl][pl] = f2bf(in[(size_t)orig * 2048 + h0 + hl]);
  }
  __syncthreads();
  const int pp = t & 15, hq = t >> 4;
#pragma unroll
  for (int i = 0; i < 4; i++) {
    int hc = i * 16 + hq;
    uint2 vv = *(const uint2*)&ls[hc][pp * 4];
    *(uint2*)&out[(size_t)(h0 + hc) * 8640 + p0 + pp * 4] = vv;
  }
}

__device__ __forceinline__ void conv_tile(const float* __restrict__ in,
                                          u16* __restrict__ out, int R, int C,
                                          int tile, u16 (*ls)[68], int t)
{
  const int tiles_c = C >> 6;
  const int r0 = (tile / tiles_c) << 6;
  const int c0 = (tile % tiles_c) << 6;
  const int cl = t & 63, q = t >> 6;
#pragma unroll
  for (int i = 0; i < 16; i++) {
    int rl = i * 4 + q;
    ls[cl][rl] = f2bf(in[(size_t)(r0 + rl) * C + c0 + cl]);
  }
  __syncthreads();
  const int pp = t & 15, cq = t >> 4;
#pragma unroll
  for (int i = 0; i < 4; i++) {
    int cc = i * 16 + cq;
    uint2 vv = *(const uint2*)&ls[cc][pp * 4];
    *(uint2*)&out[(size_t)(c0 + cc) * R + r0 + pp * 4] = vv;
  }
}

__global__ __launch_bounds__(256) void transpose_all(
    const float* __restrict__ W1,  u16* __restrict__ w1t,
    const float* __restrict__ Wh1, u16* __restrict__ wh1t,
    const float* __restrict__ Wh2, u16* __restrict__ wh2t,
    const float* __restrict__ W2,  u16* __restrict__ w2t)
{
  __shared__ u16 ls[64][68];
  const int bid = blockIdx.x, t = threadIdx.x;
  if (bid < 4320)       w1_tile(W1, w1t, bid, ls, t);
  else if (bid < 5344)  conv_tile(Wh1, wh1t, 2048, 2048, bid - 4320, ls, t);
  else if (bid < 6368)  conv_tile(Wh2, wh2t, 2048, 2048, bid - 5344, ls, t);
  else                  conv_tile(W2,  w2t,  2048, 64,   bid - 6368, ls, t);
}

// ======== gemm8p (R6 structure, 32x32x16 MFMA): C = relu(A*BT^T + bias) ====
// BM=256 BN=128 BK=64. 8 waves = 2 kg x (2Mx2N); wave tile 128x64 as 4x2
// frags of 32x32 (acc f32x16). Same verified staging + T2 slot-XOR swizzle +
// ring-3 + counted vmcnt + one barrier/interval as R6/R8. 32x32x16 raises
// MFMA floor 845->1015 FLOP/cyc/SIMD at identical LDS traffic. Reader bank
// pattern re-derived: lanes uniform over 8 16B-slot classes -> conflict-free.
__global__ __launch_bounds__(512, 2) void gemm8p(
    const u16* __restrict__ A, const u16* __restrict__ BT,
    const float* __restrict__ bias, u16* __restrict__ out,
    int N, int Kd)
{
  extern __shared__ u16 lds[];   // 3 * 24576 u16 = 144KB
  const int t = threadIdx.x, l = t & 63, w = t >> 6;
  const int nb = N >> 7;
  const int cpx = gridDim.x >> 3;
  const int bid = (blockIdx.x & 7) * cpx + (blockIdx.x >> 3);
  const int bm = bid / nb, bn = bid % nb;
  const int m0 = bm << 8, n0 = bn << 7;

  const int kg = w >> 2;               // K32-subgroup within BK=64
  const int p  = w & 3;
  const int vm = p >> 1, vn = p & 1;   // 2M x 2N

  const size_t lda = (size_t)Kd;
  const int NT = Kd >> 6;

  // ---- staging constants (pre-swizzled global source; R6-verified) ----
  const int sr = l >> 3;
  const int q  = (l & 7) ^ (sr & 7);
  const u16* sA = A  + (size_t)(m0 + w * 8 + sr) * lda + q * 8;
  const u16* sB = BT + (size_t)(n0 + w * 8 + sr) * lda + q * 8;
  const int dL = w * 512 + l * 8;

  // ---- reader constants (32x32 frags, swizzled ds_read) ----
  const int r31 = l & 31, hi = l >> 5;
  const int c0 = ((kg * 4 + 0 + hi) ^ (l & 7)) * 8;   // ks=0 chunk (u16)
  const int c1 = ((kg * 4 + 2 + hi) ^ (l & 7)) * 8;   // ks=1 chunk

  f32x16 acc[4][2] = {};
  bf16x8 a0[4], a1[4], b0[2], b1[2];

  auto stageT = [&](int o, int tt) {
    const size_t kt = (size_t)tt * 64;
    stage16(sA + kt,             lds + o + dL);
    stage16(sA + 64 * lda + kt,  lds + o + 4096 + dL);
    stage16(sA + 128 * lda + kt, lds + o + 8192 + dL);
    stage16(sA + 192 * lda + kt, lds + o + 12288 + dL);
    stage16(sB + kt,             lds + o + 16384 + dL);
    stage16(sB + 64 * lda + kt,  lds + o + 20480 + dL);
  };
  auto mmq = [&](const bf16x8* a, const bf16x8* b) {
    __builtin_amdgcn_s_setprio(1);
#pragma unroll
    for (int mi = 0; mi < 4; mi++)
#pragma unroll
      for (int ni = 0; ni < 2; ni++)
        acc[mi][ni] = __builtin_amdgcn_mfma_f32_32x32x16_bf16(
            a[mi], b[ni], acc[mi][ni], 0, 0, 0);
    __builtin_amdgcn_s_setprio(0);
  };

  int o0 = 0, o1 = 24576, o2 = 49152;
  stageT(o0, 0);
  if (NT > 1) {
    stageT(o1, 1);
    asm volatile("s_waitcnt vmcnt(6)" ::: "memory");
  } else {
    asm volatile("s_waitcnt vmcnt(0)" ::: "memory");
  }
  __builtin_amdgcn_s_barrier();

  for (int ti = 0; ti < NT; ++ti) {
    const bool st = (ti + 2 < NT);
    if (st) stageT(o2, ti + 2);                 // 6 vmem, non-blocking
    // 12 ds_reads: ks0 group first (2 B + 4 A), then ks1 group
#pragma unroll
    for (int ni = 0; ni < 2; ni++)
      b0[ni] = *(const bf16x8*)&lds[o0 + 16384 + (vn * 64 + ni * 32 + r31) * 64 + c0];
#pragma unroll
    for (int mi = 0; mi < 4; mi++)
      a0[mi] = *(const bf16x8*)&lds[o0 + (vm * 128 + mi * 32 + r31) * 64 + c0];
#pragma unroll
    for (int ni = 0; ni < 2; ni++)
      b1[ni] = *(const bf16x8*)&lds[o0 + 16384 + (vn * 64 + ni * 32 + r31) * 64 + c1];
#pragma unroll
    for (int mi = 0; mi < 4; mi++)
      a1[mi] = *(const bf16x8*)&lds[o0 + (vm * 128 + mi * 32 + r31) * 64 + c1];
    asm volatile("s_waitcnt lgkmcnt(6)" ::: "memory");   // ks0 frags done
    __builtin_amdgcn_sched_barrier(0);
    mmq(a0, b0);                                // ks1 reads drain underneath
    asm volatile("s_waitcnt lgkmcnt(0)" ::: "memory");
    __builtin_amdgcn_sched_barrier(0);
    mmq(a1, b1);
    if (st) asm volatile("s_waitcnt vmcnt(6)" ::: "memory");
    else    asm volatile("s_waitcnt vmcnt(0)" ::: "memory");
    __builtin_amdgcn_s_barrier();
    const int tmp = o0; o0 = o1; o1 = o2; o2 = tmp;
  }

  // ---- kg-combine via LDS (per-mi chunks of 32KB), then epilogue ----
  __syncthreads();
  float* pl = (float*)lds;
#pragma unroll
  for (int mi = 0; mi < 4; mi++) {
    if (kg == 1) {
#pragma unroll
      for (int ni = 0; ni < 2; ni++)
        *(f32x16*)&pl[p * 2048 + ni * 1024 + l * 16] = acc[mi][ni];
    }
    __syncthreads();
    if (kg == 0) {
#pragma unroll
      for (int ni = 0; ni < 2; ni++) {
        f32x16 p2 = *(const f32x16*)&pl[p * 2048 + ni * 1024 + l * 16];
        const int col = n0 + vn * 64 + ni * 32 + r31;
        const float bv = bias[col];
#pragma unroll
        for (int r = 0; r < 16; r++) {
          const int row = m0 + vm * 128 + mi * 32 + (r & 3) + 8 * (r >> 2) + 4 * hi;
          float vv = acc[mi][ni][r] + p2[r] + bv;
          out[(size_t)row * N + col] = f2bf(fmaxf(vv, 0.0f));
        }
      }
    }
    __syncthreads();
  }
}

// -------- gemm4 split-K partial (R8) --------
__global__ __launch_bounds__(256, 2) void gemm4_part(
    const u16* __restrict__ A, const u16* __restrict__ BT,
    float* __restrict__ pbuf)
{
  __shared__ u16 lsA[2 * 128 * 32];
  __shared__ u16 lsB[2 * 64 * 32];
  const int t = threadIdx.x, l = t & 63, w = t >> 6;
  const int bmx = blockIdx.x & 31, sk = blockIdx.x >> 5;
  const int m0 = bmx << 7, k0 = sk << 9;
  float* pout = pbuf + (size_t)sk * 262144;
  const int wm = w >> 1, wn = w & 1;

  f32x4 acc[4][2] = {};
  const int srow = l >> 2, scol = (l & 3) * 8;

  const u16* pA0 = A  + (size_t)(m0 + w * 16 + srow)      * 2048 + scol + k0;
  const u16* pA1 = A  + (size_t)(m0 + 64 + w * 16 + srow) * 2048 + scol + k0;
  const u16* pB0 = BT + (size_t)(w * 16 + srow)           * 2048 + scol + k0;

  auto stage = [&](int buf, int kt) {
    u16* dA = lsA + buf * 4096;
    u16* dB = lsB + buf * 2048;
    stage16(pA0 + kt, dA + w * 512);
    stage16(pA1 + kt, dA + 2048 + w * 512);
    stage16(pB0 + kt, dB + w * 512);
  };

  stage(0, 0);
  __syncthreads();

  const int kk = (l >> 4) * 8;
  const int rl = l & 15;
  int cur = 0;
  for (int kt = 0; kt < 512; kt += 32) {
    if (kt + 32 < 512) stage(cur ^ 1, kt + 32);
    const u16* sA = lsA + cur * 4096;
    const u16* sB = lsB + cur * 2048;
    bf16x8 a[4], bb[2];
#pragma unroll
    for (int mi = 0; mi < 4; mi++)
      a[mi] = *(const bf16x8*)&sA[(wm * 64 + mi * 16 + rl) * 32 + kk];
#pragma unroll
    for (int ni = 0; ni < 2; ni++)
      bb[ni] = *(const bf16x8*)&sB[(wn * 32 + ni * 16 + rl) * 32 + kk];
#pragma unroll
    for (int mi = 0; mi < 4; mi++)
#pragma unroll
      for (int ni = 0; ni < 2; ni++)
        acc[mi][ni] = __builtin_amdgcn_mfma_f32_16x16x32_bf16(a[mi], bb[ni], acc[mi][ni], 0, 0, 0);
    __syncthreads();
    cur ^= 1;
  }

  const int rq = l >> 4, rl2 = l & 15;
#pragma unroll
  for (int mi = 0; mi < 4; mi++)
#pragma unroll
    for (int ni = 0; ni < 2; ni++) {
      const int col = wn * 32 + ni * 16 + rl2;
#pragma unroll
      for (int j = 0; j < 4; j++) {
        const int row = m0 + wm * 64 + mi * 16 + rq * 4 + j;
        pout[(size_t)row * 64 + col] = acc[mi][ni][j];
      }
    }
}

// -------- combine: sum 4 partials + bias -> sigmoid + BCE partials --------
__global__ __launch_bounds__(256) void gemm4_combine(
    const float* __restrict__ pbuf, const float* __restrict__ bias,
    const float* __restrict__ oneh, float* __restrict__ dist,
    float* __restrict__ part2)
{
  __shared__ float red[256];
  const int t = threadIdx.x;
  const size_t base = (size_t)blockIdx.x * 1024 + t * 4;
  f32x4 s = *(const f32x4*)&pbuf[base];
  s += *(const f32x4*)&pbuf[base + 262144];
  s += *(const f32x4*)&pbuf[base + 524288];
  s += *(const f32x4*)&pbuf[base + 786432];
  const int col0 = (int)(base & 63);
  f32x4 th = *(const f32x4*)&oneh[base];
  float lsum = 0.0f;
  f32x4 dv;
#pragma unroll
  for (int j = 0; j < 4; j++) {
    const float x = s[j] + bias[col0 + j];
    dv[j] = 1.0f / (1.0f + expf(-x));
    lsum += fmaxf(x, 0.0f) - x * th[j] + log1pf(expf(-fabsf(x)));
  }
  *(f32x4*)&dist[base] = dv;
  red[t] = lsum;
  __syncthreads();
  for (int s2 = 128; s2 > 0; s2 >>= 1) {
    if (t < s2) red[t] += red[t + s2];
    __syncthreads();
  }
  if (t == 0) part2[blockIdx.x] = red[0];
}

__global__ void loss_final(const float* __restrict__ part2, float* __restrict__ outloss) {
  const int l = threadIdx.x;
  float v = 0.0f;
#pragma unroll
  for (int i = 0; i < 4; i++) v += part2[l + i * 64];
  v = wred(v);
  if (l == 0) outloss[0] = v * (1.0f / 262144.0f);
}

// ---------------- launch ----------------
extern "C" void kernel_launch(void* const* d_in, const int* in_sizes, int n_in,
                              void* d_out, int out_size, void* d_ws, size_t ws_size,
                              hipStream_t stream)
{
  const float* te   = (const float*)d_in[0];
  const int*   nidx = (const int*)  d_in[1];
  const float* oneh = (const float*)d_in[2];
  const float* freq = (const float*)d_in[3];
  const float* lut  = (const float*)d_in[4];
  const float* W1   = (const float*)d_in[5];
  const float* b1   = (const float*)d_in[6];
  const float* Wh1  = (const float*)d_in[7];
  const float* bh1  = (const float*)d_in[8];
  const float* Wh2  = (const float*)d_in[9];
  const float* bh2  = (const float*)d_in[10];
  const float* W2   = (const float*)d_in[11];
  const float* b2   = (const float*)d_in[12];

  float* dist  = (float*)d_out;          // 4096*64
  float* lossp = dist + 262144;          // +1

  size_t off = 0;
  char* base = (char*)d_ws;
  auto alloc = [&](size_t bytes) { char* p = base + off; off += (bytes + 255) & ~(size_t)255; return p; };
  u16* inp   = (u16*)alloc((size_t)4096 * 8640 * 2);
  u16* w1t   = (u16*)alloc((size_t)2048 * 8640 * 2);
  u16* wh1t  = (u16*)alloc((size_t)2048 * 2048 * 2);
  u16* wh2t  = (u16*)alloc((size_t)2048 * 2048 * 2);
  u16* w2t   = (u16*)alloc((size_t)64 * 2048 * 2);
  u16* h1    = (u16*)alloc((size_t)4096 * 2048 * 2);
  float* part2 = (float*)alloc(1024);
  u16* h2 = inp;                  // inp dead after GEMM1
  u16* h3 = w1t;                  // w1t dead after GEMM1
  float* pbuf = (float*)wh1t;     // wh1t dead after GEMM2; 4MB < 8.4MB
  if (off > ws_size) return;

  (void)hipFuncSetAttribute((const void*)gemm8p,
                            hipFuncAttributeMaxDynamicSharedMemorySize, 147456);

  feature_kernel<<<4096, 256, 0, stream>>>(te, nidx, freq, lut, inp);
  transpose_all<<<6400, 256, 0, stream>>>(W1, w1t, Wh1, wh1t, Wh2, wh2t, W2, w2t);

  gemm8p<<<256, 512, 147456, stream>>>(inp, w1t, b1, h1, 2048, 8640);
  gemm8p<<<256, 512, 147456, stream>>>(h1, wh1t, bh1, h2, 2048, 2048);
  gemm8p<<<256, 512, 147456, stream>>>(h2, wh2t, bh2, h3, 2048, 2048);
  gemm4_part   <<<128, 256, 0, stream>>>(h3, w2t, pbuf);
  gemm4_combine<<<256, 256, 0, stream>>>(pbuf, b2, oneh, dist, part2);
  loss_final   <<<1, 64, 0, stream>>>(part2, lossp);
}

// Round 11
// 326.115 us; speedup vs baseline: 1.8418x; 1.1112x over previous
//
#include <hip/hip_runtime.h>

typedef unsigned short u16;
typedef unsigned int   u32;
typedef __attribute__((ext_vector_type(8))) __bf16 bf16x8;
typedef __attribute__((ext_vector_type(4))) float  f32x4;
typedef __attribute__((ext_vector_type(4))) u32    u32x4;

#define AS1 __attribute__((address_space(1)))
#define AS3 __attribute__((address_space(3)))

// B=4096, K=64, D=128, H=2048, V=10000, IN=8640
// Permuted inp layout per row: [0,128) u | [128,8320) v | [8320,8576) extras | [8576,8640) pop

__device__ __forceinline__ u16 f2bf(float f) {
  u32 u = __builtin_bit_cast(u32, f);
  u += 0x7fffu + ((u >> 16) & 1u);   // RNE
  return (u16)(u >> 16);
}

__device__ __forceinline__ float wred(float v) {
#pragma unroll
  for (int off = 32; off > 0; off >>= 1) v += __shfl_xor(v, off, 64);
  return v;
}

__device__ __forceinline__ void stage16(const u16* g, u16* l) {
  __builtin_amdgcn_global_load_lds((const AS1 void*)g, (AS3 void*)l, 16, 0, 0);
}

// ---------------- feature kernel v2 (R8) ----------------
__global__ __launch_bounds__(256) void feature_kernel(
    const float* __restrict__ te, const int* __restrict__ nidx,
    const float* __restrict__ freq, const float* __restrict__ lut,
    u16* __restrict__ inp)
{
  const int b = blockIdx.x;
  const int t = threadIdx.x;
  const int l = t & 63, w = t >> 6;
  __shared__ float u_sh[128];
  __shared__ float squ_sh;

  if (t < 128) u_sh[t] = te[(size_t)b * 128 + t];
  __syncthreads();
  if (w == 0) {
    float p = u_sh[l] * u_sh[l] + u_sh[l + 64] * u_sh[l + 64];
    p = wred(p);
    if (l == 0) squ_sh = p;
  }
  const size_t rb = (size_t)b * 8640;
  if (t < 64) {
    float2 u2 = *(const float2*)&u_sh[t * 2];
    u32 pk = (u32)f2bf(u2.x) | ((u32)f2bf(u2.y) << 16);
    *(u32*)&inp[rb + t * 2] = pk;
  }
  __syncthreads();

  const float squ = squ_sh;
  const float rsq = 1.0f - squ;
  const float2 u2 = *(const float2*)&u_sh[l * 2];

#pragma unroll
  for (int mk = 0; mk < 4; ++mk) {
    const int kbase = w * 16 + mk * 4;
    int idx[4]; float2 v2[4]; float sqv[4], dot[4];
#pragma unroll
    for (int j = 0; j < 4; j++) {
      idx[j] = nidx[b * 64 + kbase + j];
      v2[j] = *(const float2*)&lut[(size_t)idx[j] * 128 + l * 2];
    }
#pragma unroll
    for (int j = 0; j < 4; j++) {
      sqv[j] = v2[j].x * v2[j].x + v2[j].y * v2[j].y;
      dot[j] = u2.x * v2[j].x + u2.y * v2[j].y;
    }
#pragma unroll
    for (int off = 32; off > 0; off >>= 1) {
#pragma unroll
      for (int j = 0; j < 4; j++) {
        sqv[j] += __shfl_xor(sqv[j], off, 64);
        dot[j] += __shfl_xor(dot[j], off, 64);
      }
    }
#pragma unroll
    for (int j = 0; j < 4; j++) {
      u32 pk = (u32)f2bf(v2[j].x) | ((u32)f2bf(v2[j].y) << 16);
      *(u32*)&inp[rb + 128 + (size_t)(kbase + j) * 128 + l * 2] = pk;
    }
    float poin[4], cosv[4];
#pragma unroll
    for (int j = 0; j < 4; j++) {
      const float sqd = squ + sqv[j] - 2.0f * dot[j];
      float x = 1.0f + 2.0f * sqd / (rsq * (1.0f - sqv[j]));
      x = fmaxf(x, 1.0f + 1e-5f);
      poin[j] = logf(x + sqrtf(x * x - 1.0f));
      cosv[j] = dot[j] / fmaxf(sqrtf(squ * sqv[j]), 1e-8f);
    }
    if (l == 0) {
      u32x4 e0, e1;
#pragma unroll
      for (int j = 0; j < 2; j++) {
        e0[2 * j]     = (u32)f2bf(poin[j]) | ((u32)f2bf(cosv[j]) << 16);
        e0[2 * j + 1] = (u32)f2bf(dot[j])  | ((u32)f2bf(dot[j])  << 16);
        e1[2 * j]     = (u32)f2bf(poin[2 + j]) | ((u32)f2bf(cosv[2 + j]) << 16);
        e1[2 * j + 1] = (u32)f2bf(dot[2 + j])  | ((u32)f2bf(dot[2 + j])  << 16);
      }
      *(u32x4*)&inp[rb + 8320 + kbase * 4]     = e0;
      *(u32x4*)&inp[rb + 8320 + kbase * 4 + 8] = e1;
      u16 pp[4];
#pragma unroll
      for (int j = 0; j < 4; j++) pp[j] = f2bf(log1pf(freq[idx[j]]));
      *(u32*)&inp[rb + 8576 + kbase]     = (u32)pp[0] | ((u32)pp[1] << 16);
      *(u32*)&inp[rb + 8576 + kbase + 2] = (u32)pp[2] | ((u32)pp[3] << 16);
    }
  }
}

// -------- fused transpose kernel: W1 (permuted) + Wh1 + Wh2 + W2 --------
__device__ __forceinline__ int w1_orig_row(int p) {
  if (p < 128) return p;
  if (p < 8320) { int q = p - 128;  return 128 + (q >> 7) * 133 + (q & 127); }
  if (p < 8576) { int q = p - 8320; return 128 + (q >> 2) * 133 + 128 + (q & 3); }
  return 128 + (p - 8576) * 133 + 132;
}

__device__ __forceinline__ void w1_tile(const float* __restrict__ in,
                                        u16* __restrict__ out, int tile,
                                        u16 (*ls)[68], int t)
{
  const int p0 = (tile >> 5) << 6;
  const int h0 = (tile & 31) << 6;
  const int hl = t & 63, q = t >> 6;
#pragma unroll
  for (int i = 0; i < 16; i++) {
    int pl = i * 4 + q;
    int orig = w1_orig_row(p0 + pl);
    ls[hl][pl] = f2bf(in[(size_t)orig * 2048 + h0 + hl]);
  }
  __syncthreads();
  const int pp = t & 15, hq = t >> 4;
#pragma unroll
  for (int i = 0; i < 4; i++) {
    int hc = i * 16 + hq;
    uint2 vv = *(const uint2*)&ls[hc][pp * 4];
    *(uint2*)&out[(size_t)(h0 + hc) * 8640 + p0 + pp * 4] = vv;
  }
}

__device__ __forceinline__ void conv_tile(const float* __restrict__ in,
                                          u16* __restrict__ out, int R, int C,
                                          int tile, u16 (*ls)[68], int t)
{
  const int tiles_c = C >> 6;
  const int r0 = (tile / tiles_c) << 6;
  const int c0 = (tile % tiles_c) << 6;
  const int cl = t & 63, q = t >> 6;
#pragma unroll
  for (int i = 0; i < 16; i++) {
    int rl = i * 4 + q;
    ls[cl][rl] = f2bf(in[(size_t)(r0 + rl) * C + c0 + cl]);
  }
  __syncthreads();
  const int pp = t & 15, cq = t >> 4;
#pragma unroll
  for (int i = 0; i < 4; i++) {
    int cc = i * 16 + cq;
    uint2 vv = *(const uint2*)&ls[cc][pp * 4];
    *(uint2*)&out[(size_t)(c0 + cc) * R + r0 + pp * 4] = vv;
  }
}

__global__ __launch_bounds__(256) void transpose_all(
    const float* __restrict__ W1,  u16* __restrict__ w1t,
    const float* __restrict__ Wh1, u16* __restrict__ wh1t,
    const float* __restrict__ Wh2, u16* __restrict__ wh2t,
    const float* __restrict__ W2,  u16* __restrict__ w2t)
{
  __shared__ u16 ls[64][68];
  const int bid = blockIdx.x, t = threadIdx.x;
  if (bid < 4320)       w1_tile(W1, w1t, bid, ls, t);
  else if (bid < 5344)  conv_tile(Wh1, wh1t, 2048, 2048, bid - 4320, ls, t);
  else if (bid < 6368)  conv_tile(Wh2, wh2t, 2048, 2048, bid - 5344, ls, t);
  else                  conv_tile(W2,  w2t,  2048, 64,   bid - 6368, ls, t);
}

// ======== gemm2b: C(M,N) = relu(A(M,Kd)*BT(N,Kd)^T + bias), out bf16 ========
// BM=128 BN=128 BK=64. 256 thr = 4 waves (2Mx2N), wave tile 64x64 acc[4][4]
// (16x16x32 MFMA — the R8-verified mapping). Ring-2 x 32KB = 64KB LDS ->
// 2 blocks/CU: inter-block TLP overlaps one block's LDS streams with the
// other's MFMA (m114), which intra-block scheduling provably can't (R5/R6:
// symmetric waves serialize; serial model validated +-1%). Per interval:
// vmcnt(0) on the interval-old stage -> barrier -> issue stage(ti+1) ->
// 16 swizzled ds_reads -> lgkm(8) -> 16 MFMA -> lgkm(0) -> 16 MFMA.
// Stage issue AFTER the entry barrier: reads(ti) (drained via lgkm(0)
// before that barrier) strictly precede any overwrite of buf(ti) — the
// ring-2 race is closed with ONE barrier/interval. T2 slot-XOR swizzle
// both-sides (R6-verified formulas, 0 conflicts on HW).
__global__ __launch_bounds__(256, 2) void gemm2b(
    const u16* __restrict__ A, const u16* __restrict__ BT,
    const float* __restrict__ bias, u16* __restrict__ out,
    int N, int Kd)
{
  extern __shared__ u16 lds[];   // 2 * 16384 u16 = 64KB
  const int t = threadIdx.x, l = t & 63, w = t >> 6;
  const int nb = N >> 7;
  const int cpx = gridDim.x >> 3;
  const int bid = (blockIdx.x & 7) * cpx + (blockIdx.x >> 3);
  const int bm = bid / nb, bn = bid % nb;
  const int m0 = bm << 7, n0 = bn << 7;
  const int vm = w >> 1, vn = w & 1;

  const size_t lda = (size_t)Kd;
  const int NT = Kd >> 6;

  // ---- staging constants (pre-swizzled global source; R6-verified) ----
  const int sr = l >> 3;
  const int q  = (l & 7) ^ sr;
  const u16* sA = A  + (size_t)(m0 + w * 32 + sr) * lda + q * 8;
  const u16* sB = BT + (size_t)(n0 + w * 32 + sr) * lda + q * 8;
  const int dW = w * 2048;   // u16; per-buffer A at 0, B at 8192

  // ---- reader constants (swizzled ds_read; R6-verified formula) ----
  const int rl = l & 15;
  const int c0 = ((0 + (l >> 4)) ^ (rl & 7)) * 8;   // ks=0 chunk
  const int c1 = ((4 + (l >> 4)) ^ (rl & 7)) * 8;   // ks=1 chunk
  const int aBase = (vm * 64 + rl) * 64;            // + mi*1024
  const int bBase = 8192 + (vn * 64 + rl) * 64;     // + ni*1024

  f32x4 acc[4][4] = {};
  bf16x8 a0[4], a1[4], b0[4], b1[4];

  auto stageT = [&](int o, int tt) {
    const size_t kt = (size_t)tt * 64;
#pragma unroll
    for (int i = 0; i < 4; i++) {
      stage16(sA + (size_t)i * 8 * lda + kt, lds + o + dW + i * 512);
      stage16(sB + (size_t)i * 8 * lda + kt, lds + o + 8192 + dW + i * 512);
    }
  };
  auto mmq = [&](const bf16x8* a, const bf16x8* b) {
    __builtin_amdgcn_s_setprio(1);
#pragma unroll
    for (int mi = 0; mi < 4; mi++)
#pragma unroll
      for (int ni = 0; ni < 4; ni++)
        acc[mi][ni] = __builtin_amdgcn_mfma_f32_16x16x32_bf16(a[mi], b[ni], acc[mi][ni], 0, 0, 0);
    __builtin_amdgcn_s_setprio(0);
  };

  stageT(0, 0);   // prologue: tile 0 into buf0

  for (int ti = 0; ti < NT; ++ti) {
    const int o  = (ti & 1) ? 16384 : 0;
    const int on = o ^ 16384;
    // entry: my stage(ti) writes done (issued a full interval ago)
    asm volatile("s_waitcnt vmcnt(0)" ::: "memory");
    __builtin_amdgcn_s_barrier();   // all stage(ti) visible; all reads(ti-1) done
    if (ti + 1 < NT) stageT(on, ti + 1);   // overwrites buf(ti-1): reads drained pre-barrier
    // 16 ds_reads: half0 group (b0,a0) first, then half1
#pragma unroll
    for (int x = 0; x < 4; x++) b0[x] = *(const bf16x8*)&lds[o + bBase + x * 1024 + c0];
#pragma unroll
    for (int x = 0; x < 4; x++) a0[x] = *(const bf16x8*)&lds[o + aBase + x * 1024 + c0];
#pragma unroll
    for (int x = 0; x < 4; x++) b1[x] = *(const bf16x8*)&lds[o + bBase + x * 1024 + c1];
#pragma unroll
    for (int x = 0; x < 4; x++) a1[x] = *(const bf16x8*)&lds[o + aBase + x * 1024 + c1];
    asm volatile("s_waitcnt lgkmcnt(8)" ::: "memory");   // half0 frags landed
    __builtin_amdgcn_sched_barrier(0);
    mmq(a0, b0);                      // half1 reads drain underneath
    asm volatile("s_waitcnt lgkmcnt(0)" ::: "memory");
    __builtin_amdgcn_sched_barrier(0);
    mmq(a1, b1);
  }

  // ---- epilogue: direct bias+relu+store (disjoint 64x64 wave tiles) ----
  const int rq = l >> 4, rl2 = l & 15;
#pragma unroll
  for (int mi = 0; mi < 4; mi++) {
#pragma unroll
    for (int ni = 0; ni < 4; ni++) {
      const int col = n0 + vn * 64 + ni * 16 + rl2;
      const float bv = bias[col];
#pragma unroll
      for (int j = 0; j < 4; j++) {
        const int row = m0 + vm * 64 + mi * 16 + rq * 4 + j;
        float vv = acc[mi][ni][j] + bv;
        out[(size_t)row * N + col] = f2bf(fmaxf(vv, 0.0f));
      }
    }
  }
}

// -------- gemm4 split-K partial (R8) --------
__global__ __launch_bounds__(256, 2) void gemm4_part(
    const u16* __restrict__ A, const u16* __restrict__ BT,
    float* __restrict__ pbuf)
{
  __shared__ u16 lsA[2 * 128 * 32];
  __shared__ u16 lsB[2 * 64 * 32];
  const int t = threadIdx.x, l = t & 63, w = t >> 6;
  const int bmx = blockIdx.x & 31, sk = blockIdx.x >> 5;
  const int m0 = bmx << 7, k0 = sk << 9;
  float* pout = pbuf + (size_t)sk * 262144;
  const int wm = w >> 1, wn = w & 1;

  f32x4 acc[4][2] = {};
  const int srow = l >> 2, scol = (l & 3) * 8;

  const u16* pA0 = A  + (size_t)(m0 + w * 16 + srow)      * 2048 + scol + k0;
  const u16* pA1 = A  + (size_t)(m0 + 64 + w * 16 + srow) * 2048 + scol + k0;
  const u16* pB0 = BT + (size_t)(w * 16 + srow)           * 2048 + scol + k0;

  auto stage = [&](int buf, int kt) {
    u16* dA = lsA + buf * 4096;
    u16* dB = lsB + buf * 2048;
    stage16(pA0 + kt, dA + w * 512);
    stage16(pA1 + kt, dA + 2048 + w * 512);
    stage16(pB0 + kt, dB + w * 512);
  };

  stage(0, 0);
  __syncthreads();

  const int kk = (l >> 4) * 8;
  const int rl = l & 15;
  int cur = 0;
  for (int kt = 0; kt < 512; kt += 32) {
    if (kt + 32 < 512) stage(cur ^ 1, kt + 32);
    const u16* sA = lsA + cur * 4096;
    const u16* sB = lsB + cur * 2048;
    bf16x8 a[4], bb[2];
#pragma unroll
    for (int mi = 0; mi < 4; mi++)
      a[mi] = *(const bf16x8*)&sA[(wm * 64 + mi * 16 + rl) * 32 + kk];
#pragma unroll
    for (int ni = 0; ni < 2; ni++)
      bb[ni] = *(const bf16x8*)&sB[(wn * 32 + ni * 16 + rl) * 32 + kk];
#pragma unroll
    for (int mi = 0; mi < 4; mi++)
#pragma unroll
      for (int ni = 0; ni < 2; ni++)
        acc[mi][ni] = __builtin_amdgcn_mfma_f32_16x16x32_bf16(a[mi], bb[ni], acc[mi][ni], 0, 0, 0);
    __syncthreads();
    cur ^= 1;
  }

  const int rq = l >> 4, rl2 = l & 15;
#pragma unroll
  for (int mi = 0; mi < 4; mi++)
#pragma unroll
    for (int ni = 0; ni < 2; ni++) {
      const int col = wn * 32 + ni * 16 + rl2;
#pragma unroll
      for (int j = 0; j < 4; j++) {
        const int row = m0 + wm * 64 + mi * 16 + rq * 4 + j;
        pout[(size_t)row * 64 + col] = acc[mi][ni][j];
      }
    }
}

// -------- combine: sum 4 partials + bias -> sigmoid + BCE partials --------
__global__ __launch_bounds__(256) void gemm4_combine(
    const float* __restrict__ pbuf, const float* __restrict__ bias,
    const float* __restrict__ oneh, float* __restrict__ dist,
    float* __restrict__ part2)
{
  __shared__ float red[256];
  const int t = threadIdx.x;
  const size_t base = (size_t)blockIdx.x * 1024 + t * 4;
  f32x4 s = *(const f32x4*)&pbuf[base];
  s += *(const f32x4*)&pbuf[base + 262144];
  s += *(const f32x4*)&pbuf[base + 524288];
  s += *(const f32x4*)&pbuf[base + 786432];
  const int col0 = (int)(base & 63);
  f32x4 th = *(const f32x4*)&oneh[base];
  float lsum = 0.0f;
  f32x4 dv;
#pragma unroll
  for (int j = 0; j < 4; j++) {
    const float x = s[j] + bias[col0 + j];
    dv[j] = 1.0f / (1.0f + expf(-x));
    lsum += fmaxf(x, 0.0f) - x * th[j] + log1pf(expf(-fabsf(x)));
  }
  *(f32x4*)&dist[base] = dv;
  red[t] = lsum;
  __syncthreads();
  for (int s2 = 128; s2 > 0; s2 >>= 1) {
    if (t < s2) red[t] += red[t + s2];
    __syncthreads();
  }
  if (t == 0) part2[blockIdx.x] = red[0];
}

__global__ void loss_final(const float* __restrict__ part2, float* __restrict__ outloss) {
  const int l = threadIdx.x;
  float v = 0.0f;
#pragma unroll
  for (int i = 0; i < 4; i++) v += part2[l + i * 64];
  v = wred(v);
  if (l == 0) outloss[0] = v * (1.0f / 262144.0f);
}

// ---------------- launch ----------------
extern "C" void kernel_launch(void* const* d_in, const int* in_sizes, int n_in,
                              void* d_out, int out_size, void* d_ws, size_t ws_size,
                              hipStream_t stream)
{
  const float* te   = (const float*)d_in[0];
  const int*   nidx = (const int*)  d_in[1];
  const float* oneh = (const float*)d_in[2];
  const float* freq = (const float*)d_in[3];
  const float* lut  = (const float*)d_in[4];
  const float* W1   = (const float*)d_in[5];
  const float* b1   = (const float*)d_in[6];
  const float* Wh1  = (const float*)d_in[7];
  const float* bh1  = (const float*)d_in[8];
  const float* Wh2  = (const float*)d_in[9];
  const float* bh2  = (const float*)d_in[10];
  const float* W2   = (const float*)d_in[11];
  const float* b2   = (const float*)d_in[12];

  float* dist  = (float*)d_out;          // 4096*64
  float* lossp = dist + 262144;          // +1

  size_t off = 0;
  char* base = (char*)d_ws;
  auto alloc = [&](size_t bytes) { char* p = base + off; off += (bytes + 255) & ~(size_t)255; return p; };
  u16* inp   = (u16*)alloc((size_t)4096 * 8640 * 2);
  u16* w1t   = (u16*)alloc((size_t)2048 * 8640 * 2);
  u16* wh1t  = (u16*)alloc((size_t)2048 * 2048 * 2);
  u16* wh2t  = (u16*)alloc((size_t)2048 * 2048 * 2);
  u16* w2t   = (u16*)alloc((size_t)64 * 2048 * 2);
  u16* h1    = (u16*)alloc((size_t)4096 * 2048 * 2);
  float* part2 = (float*)alloc(1024);
  u16* h2 = inp;                  // inp dead after GEMM1
  u16* h3 = w1t;                  // w1t dead after GEMM1
  float* pbuf = (float*)wh1t;     // wh1t dead after GEMM2; 4MB < 8.4MB
  if (off > ws_size) return;

  (void)hipFuncSetAttribute((const void*)gemm2b,
                            hipFuncAttributeMaxDynamicSharedMemorySize, 65536);

  feature_kernel<<<4096, 256, 0, stream>>>(te, nidx, freq, lut, inp);
  transpose_all<<<6400, 256, 0, stream>>>(W1, w1t, Wh1, wh1t, Wh2, wh2t, W2, w2t);

  gemm2b<<<512, 256, 65536, stream>>>(inp, w1t, b1, h1, 2048, 8640);
  gemm2b<<<512, 256, 65536, stream>>>(h1, wh1t, bh1, h2, 2048, 2048);
  gemm2b<<<512, 256, 65536, stream>>>(h2, wh2t, bh2, h3, 2048, 2048);
  gemm4_part   <<<128, 256, 0, stream>>>(h3, w2t, pbuf);
  gemm4_combine<<<256, 256, 0, stream>>>(pbuf, b2, oneh, dist, part2);
  loss_final   <<<1, 64, 0, stream>>>(part2, lossp);
}